// Round 12
// baseline (530.221 us; speedup 1.0000x reference)
//
#include <hip/hip_runtime.h>
#include <hip/hip_bf16.h>

typedef unsigned short u16;
typedef unsigned int   u32;
typedef __attribute__((ext_vector_type(8))) __bf16 bf16x8;
typedef __attribute__((ext_vector_type(4))) float  f32x4;

#define EPSQ 1e-7f
#define KSPLIT 9
#define KPB 2304
#define KSTEPS 36
#define FC3SPL 8

#define GLDS16(gp, lp) __builtin_amdgcn_global_load_lds( \
    (const __attribute__((address_space(1))) void*)(gp), \
    (__attribute__((address_space(3))) void*)(lp), 16, 0, 0)
#define WAITV8() asm volatile("s_waitcnt vmcnt(8)" ::: "memory")
#define WAITV0() asm volatile("s_waitcnt vmcnt(0)" ::: "memory")

__device__ __forceinline__ u16 f2bf(float f){
  u32 u = __float_as_uint(f);
  u32 r = (u + 0x7fffu + ((u >> 16) & 1u)) >> 16;
  return (u16)r;
}
__device__ __forceinline__ float bf2f(u16 h){ return __uint_as_float(((u32)h) << 16); }
__device__ __forceinline__ float blo(u32 w){ return __uint_as_float(w << 16); }
__device__ __forceinline__ float bhi(u32 w){ return __uint_as_float(w & 0xffff0000u); }

// ---------------- im2col for conv1: A1[m][k] bf16, k=(ky*9+kx)*3+ic (<243), pad to 256
__global__ __launch_bounds__(256) void k_im2col(const float* __restrict__ x, u16* __restrict__ A1){
  const int id = blockIdx.x*256 + threadIdx.x;
  const int m  = id >> 5;
  const int s  = id & 31;
  const int b  = m / 3136;
  const int r  = m - b*3136;
  const int oy = r / 56;
  const int ox = r - oy*56;
  const float* xb = x + ((size_t)b*120 + 2*oy)*120*3 + 2*ox*3;
  u16 vals[8];
  #pragma unroll
  for (int j=0;j<8;++j){
    int k = s*8 + j;
    if (k < 243){
      int ky = k / 27;
      int rem = k - ky*27;
      vals[j] = f2bf(xb[(size_t)ky*360 + rem]);
    } else vals[j] = 0;
  }
  *reinterpret_cast<uint4*>(A1 + (size_t)m*256 + s*8) = *reinterpret_cast<uint4*>(vals);
}

// ---------------- transpose+pad conv1_w (243,256) f32 -> (256,256) bf16
__global__ __launch_bounds__(256) void k_wt1(const float* __restrict__ w, u16* __restrict__ wt){
  __shared__ float tile[32][33];
  const int k0 = blockIdx.x*32;
  const int c0 = blockIdx.y*32;
  const int c  = threadIdx.x & 31;
  const int r8 = threadIdx.x >> 5;
  #pragma unroll
  for (int rr=0; rr<4; ++rr){
    int r = r8*4+rr;
    tile[r][c] = (k0+r < 243) ? w[(size_t)(k0+r)*256 + c0 + c] : 0.f;
  }
  __syncthreads();
  #pragma unroll
  for (int rr=0; rr<4; ++rr){
    int r = r8*4+rr;
    wt[(size_t)(c0+r)*256 + k0 + c] = f2bf(tile[c][r]);
  }
}

// ---------------- conv1 GEMM: M=100352, N=256, K=256 ; BK=64, depth-2, dual-swizzled
__global__ __launch_bounds__(256) void k_gemm1(const u16* __restrict__ A1,
    const u16* __restrict__ w1t, const float* __restrict__ bias, u16* __restrict__ a1b){
  __shared__ __align__(16) u16 As[2][8192];   // [128 rows][64 k], 128B rows (8 slots of 16B)
  __shared__ __align__(16) u16 Bs[2][8192];
  const int t  = threadIdx.x;
  const int bx = blockIdx.x;   // 784
  const int by = blockIdx.y;   // 2
  const int r8 = t>>3;                       // staging row within 32-row group
  const int sslot = (t&7) ^ (r8&7);          // pre-swizzled source k-slot
  const int wid = t>>6, lane = t&63;
  const int wr = wid>>1, wc = wid&1, lr = lane&15, lq = lane>>4;
  size_t gA[4], gB[4];
  #pragma unroll
  for (int i=0;i<4;++i){
    gA[i] = (size_t)(bx*128 + i*32 + r8)*256 + sslot*8;
    gB[i] = (size_t)(by*128 + i*32 + r8)*256 + sslot*8;
  }
  f32x4 acc[4][4];
  #pragma unroll
  for (int i=0;i<4;++i)
    #pragma unroll
    for (int j=0;j<4;++j) acc[i][j] = (f32x4){0.f,0.f,0.f,0.f};

  auto stage = [&](int step, int buf){
    const int k0 = step*64;
    #pragma unroll
    for (int i=0;i<4;++i)
      GLDS16(A1 + gA[i] + k0, &As[buf][i*2048 + wid*512]);
    #pragma unroll
    for (int i=0;i<4;++i)
      GLDS16(w1t + gB[i] + k0, &Bs[buf][i*2048 + wid*512]);
  };
  auto compute = [&](int buf){
    #pragma unroll
    for (int ksub=0;ksub<2;++ksub){
      const int ps = (((ksub<<2)|lq) ^ (lr&7))*8;   // swizzled slot (elements)
      bf16x8 af[4], bfv[4];
      #pragma unroll
      for (int mi=0;mi<4;++mi)
        af[mi] = *reinterpret_cast<const bf16x8*>(&As[buf][(wr*64 + mi*16 + lr)*64 + ps]);
      #pragma unroll
      for (int ni=0;ni<4;++ni)
        bfv[ni] = *reinterpret_cast<const bf16x8*>(&Bs[buf][(wc*64 + ni*16 + lr)*64 + ps]);
      #pragma unroll
      for (int mi=0;mi<4;++mi)
        #pragma unroll
        for (int ni=0;ni<4;++ni)
          acc[mi][ni] = __builtin_amdgcn_mfma_f32_16x16x32_bf16(af[mi], bfv[ni], acc[mi][ni], 0, 0, 0);
    }
  };

  stage(0, 0);
  int cur = 0;
  for (int step=0; step<4; ++step){
    if (step+1 < 4){
      stage(step+1, cur^1);
      WAITV8();
    } else {
      WAITV0();
    }
    __builtin_amdgcn_s_barrier();
    __builtin_amdgcn_sched_barrier(0);
    compute(cur);
    __builtin_amdgcn_s_barrier();
    __builtin_amdgcn_sched_barrier(0);
    cur ^= 1;
  }

  #pragma unroll
  for (int ni=0;ni<4;++ni){
    int colg = by*128 + wc*64 + ni*16 + lr;
    float bv = bias[colg];
    #pragma unroll
    for (int mi=0;mi<4;++mi){
      #pragma unroll
      for (int r=0;r<4;++r){
        int rowg = bx*128 + wr*64 + mi*16 + lq*4 + r;
        float v = fmaxf(acc[mi][ni][r] + bv, 0.f);
        a1b[(size_t)rowg*256 + colg] = f2bf(v);
      }
    }
  }
}

// ---------------- transpose conv2_w (20736,128) f32 -> (128,20736) bf16
__global__ __launch_bounds__(256) void k_wt(const float* __restrict__ w, u16* __restrict__ wt){
  __shared__ float tile[32][33];
  const int k0 = blockIdx.x*32;
  const int c0 = blockIdx.y*32;
  const int c  = threadIdx.x & 31;
  const int r8 = threadIdx.x >> 5;
  #pragma unroll
  for (int rr=0; rr<4; ++rr){
    int r = r8*4+rr;
    tile[r][c] = w[(size_t)(k0+r)*128 + c0 + c];
  }
  __syncthreads();
  #pragma unroll
  for (int rr=0; rr<4; ++rr){
    int r = r8*4+rr;
    wt[(size_t)(c0+r)*20736 + k0 + c] = f2bf(tile[c][r]);
  }
}

// ---------------- conv2 implicit GEMM: M=18432, N=128, K=20736 ; BK=64, depth-2, dual-swizzled
__global__ __launch_bounds__(256) void k_conv2(const u16* __restrict__ a1b,
    const u16* __restrict__ w2t, float* __restrict__ part){
  __shared__ __align__(16) u16 As[2][8192];   // [128 rows][64 k]
  __shared__ __align__(16) u16 Bs[2][8192];
  const int t  = threadIdx.x;
  const int bx = blockIdx.x;   // 0..143
  const int ks = blockIdx.y;   // 0..KSPLIT-1 (= ky)
  const int r8 = t>>3;
  const int sslot = (t&7) ^ (r8&7);
  int gA[4]; int gB[4];
  #pragma unroll
  for (int i=0;i<4;++i){
    int m  = bx*128 + i*32 + r8;
    int bb = m/576; int r = m - bb*576; int oy = r/24; int ox = r - oy*24;
    gA[i] = ((bb*56 + 2*oy)*56 + 2*ox)*256 + sslot*8;
    int col = i*32 + r8;
    gB[i] = col*20736 + sslot*8;
  }
  const int wid = t>>6, lane = t&63;
  const int wr = wid>>1, wc = wid&1, lr = lane&15, lq = lane>>4;
  f32x4 acc[4][4];
  #pragma unroll
  for (int i=0;i<4;++i)
    #pragma unroll
    for (int j=0;j<4;++j) acc[i][j] = (f32x4){0.f,0.f,0.f,0.f};
  const int kbase = ks*KPB;

  auto stage = [&](int step, int buf){
    const int kx  = step >> 2;             // 64-k slice: kx = step/4
    const int ic0 = (step & 3) * 64;
    const int soff = (ks*56 + kx)*256 + ic0;   // ky = ks (KPB = one ky row)
    const int k0b  = kbase + step*64;
    #pragma unroll
    for (int i=0;i<4;++i)
      GLDS16(a1b + gA[i] + soff, &As[buf][i*2048 + wid*512]);
    #pragma unroll
    for (int i=0;i<4;++i)
      GLDS16(w2t + gB[i] + k0b, &Bs[buf][i*2048 + wid*512]);
  };
  auto compute = [&](int buf){
    #pragma unroll
    for (int ksub=0;ksub<2;++ksub){
      const int ps = (((ksub<<2)|lq) ^ (lr&7))*8;
      bf16x8 af[4], bfv[4];
      #pragma unroll
      for (int mi=0;mi<4;++mi)
        af[mi] = *reinterpret_cast<const bf16x8*>(&As[buf][(wr*64 + mi*16 + lr)*64 + ps]);
      #pragma unroll
      for (int ni=0;ni<4;++ni)
        bfv[ni] = *reinterpret_cast<const bf16x8*>(&Bs[buf][(wc*64 + ni*16 + lr)*64 + ps]);
      #pragma unroll
      for (int mi=0;mi<4;++mi)
        #pragma unroll
        for (int ni=0;ni<4;++ni)
          acc[mi][ni] = __builtin_amdgcn_mfma_f32_16x16x32_bf16(af[mi], bfv[ni], acc[mi][ni], 0, 0, 0);
    }
  };

  stage(0, 0);
  int cur = 0;
  for (int step=0; step<KSTEPS; ++step){
    if (step+1 < KSTEPS){
      stage(step+1, cur^1);
      WAITV8();
    } else {
      WAITV0();
    }
    __builtin_amdgcn_s_barrier();
    __builtin_amdgcn_sched_barrier(0);
    compute(cur);
    __builtin_amdgcn_s_barrier();
    __builtin_amdgcn_sched_barrier(0);
    cur ^= 1;
  }

  const size_t base = ((size_t)ks*18432 + (size_t)bx*128)*128;
  #pragma unroll
  for (int mi=0;mi<4;++mi){
    #pragma unroll
    for (int ni=0;ni<4;++ni){
      int col = wc*64 + ni*16 + lr;
      #pragma unroll
      for (int r=0;r<4;++r){
        int row = wr*64 + mi*16 + lq*4 + r;
        part[base + (size_t)row*128 + col] = acc[mi][ni][r];
      }
    }
  }
}

// ---------------- combine K-split partials + bias -> u (fp32), float4
__global__ __launch_bounds__(256) void k_comb(const float* __restrict__ part,
    const float* __restrict__ bias, float* __restrict__ u){
  const int i4 = blockIdx.x*256 + threadIdx.x;   // < 589824
  const float4* b4 = reinterpret_cast<const float4*>(bias);
  float4 s = b4[i4 & 31];
  const float4* p4 = reinterpret_cast<const float4*>(part);
  #pragma unroll
  for (int ks=0; ks<KSPLIT; ++ks){
    float4 p = p4[(size_t)ks*589824 + i4];
    s.x += p.x; s.y += p.y; s.z += p.z; s.w += p.w;
  }
  reinterpret_cast<float4*>(u)[i4] = s;
}

// ---------------- u_hat[b,c,n,d] (bf16) = sum_p W[n,c,d,p] * u[b,n,p]
__global__ __launch_bounds__(256) void k_uhat(const float* __restrict__ u,
    const float* __restrict__ wpose, u16* __restrict__ uhat){
  __shared__ float Wn[1280];
  __shared__ float us[256];
  const int n = blockIdx.x;
  const int t = threadIdx.x;
  #pragma unroll
  for (int j=0;j<5;++j) Wn[t + j*256] = wpose[(size_t)n*1280 + t + j*256];
  us[t] = u[((size_t)(t>>3)*9216 + n)*8 + (t&7)];
  __syncthreads();
  const int b = t>>3, d0 = (t&7)*2;
  float uv[8];
  #pragma unroll
  for (int p=0;p<8;++p) uv[p] = us[b*8+p];
  for (int c=0;c<10;++c){
    const float* w0 = &Wn[(c*16 + d0)*8];
    float v0=0.f, v1=0.f;
    #pragma unroll
    for (int p=0;p<8;++p){ v0 = fmaf(w0[p], uv[p], v0); v1 = fmaf(w0[8+p], uv[p], v1); }
    u32 pk = (u32)f2bf(v0) | ((u32)f2bf(v1) << 16);
    *reinterpret_cast<u32*>(uhat + ((((size_t)b*10 + c)*9216 + n)*16 + d0)) = pk;
  }
}

// ---------------- fused routing iteration (in-block squash of previous spart)
// spart layout: [b][ch][160]
template<int ITER>
__global__ __launch_bounds__(256) void k_route(const u16* __restrict__ uhat,
    const float* __restrict__ spin, float* __restrict__ logi,
    float* __restrict__ spout){
  const int ch = blockIdx.x;   // 36 chunks of 256 n
  const int b  = blockIdx.y;   // 32
  const int t  = threadIdx.x;
  const int n  = ch*256 + t;
  __shared__ float vl[160];
  __shared__ float sq[160];
  __shared__ float wlds[10][257];
  __shared__ float pacc[10][16][33];
  if (ITER >= 2){
    float sv = 0.f;
    if (t < 160){
      #pragma unroll 4
      for (int c2=0;c2<36;++c2) sv += spin[((size_t)b*36 + c2)*160 + t];
      sq[t] = sv*sv;
    }
    __syncthreads();
    if (t < 160){
      int cc = t >> 4;
      float ss = 0.f;
      #pragma unroll
      for (int j=0;j<16;++j) ss += sq[cc*16 + j];
      float nrm = sqrtf(ss);
      vl[t] = (ss/(1.f+ss)) * sv / (nrm + EPSQ);
    }
    __syncthreads();
  }
  float w[10];
  if (ITER == 1){
    #pragma unroll
    for (int c=0;c<10;++c) w[c] = 0.1f;
  } else {
    float l[10];
    #pragma unroll
    for (int c=0;c<10;++c){
      const u16* up = uhat + ((((size_t)b*10 + c)*9216 + n) << 4);
      const uint4 q0 = *reinterpret_cast<const uint4*>(up);
      const uint4 q1 = *reinterpret_cast<const uint4*>(up + 8);
      const float* v = &vl[c*16];
      float dot = blo(q0.x)*v[0] + bhi(q0.x)*v[1]
                + blo(q0.y)*v[2] + bhi(q0.y)*v[3]
                + blo(q0.z)*v[4] + bhi(q0.z)*v[5]
                + blo(q0.w)*v[6] + bhi(q0.w)*v[7]
                + blo(q1.x)*v[8] + bhi(q1.x)*v[9]
                + blo(q1.y)*v[10]+ bhi(q1.y)*v[11]
                + blo(q1.z)*v[12]+ bhi(q1.z)*v[13]
                + blo(q1.w)*v[14]+ bhi(q1.w)*v[15];
      size_t li = ((size_t)b*10 + c)*9216 + n;
      float lc = dot;
      if (ITER == 3) lc += logi[li];
      if (ITER == 2) logi[li] = lc;
      l[c] = lc;
    }
    float mx = l[0];
    #pragma unroll
    for (int c=1;c<10;++c) mx = fmaxf(mx, l[c]);
    float s = 0.f;
    #pragma unroll
    for (int c=0;c<10;++c){ w[c] = __expf(l[c]-mx); s += w[c]; }
    float inv = 1.f/s;
    #pragma unroll
    for (int c=0;c<10;++c) w[c] *= inv;
  }
  #pragma unroll
  for (int c=0;c<10;++c) wlds[c][t] = w[c];
  __syncthreads();

  const int nl = t>>3, dp = t&7;
  float a0[10], a1[10];
  #pragma unroll
  for (int c=0;c<10;++c){ a0[c]=0.f; a1[c]=0.f; }
  #pragma unroll
  for (int c=0;c<10;++c){
    const u32* ub = reinterpret_cast<const u32*>(
        uhat + ((((size_t)b*10 + c)*9216 + (size_t)ch*256) << 4));
    float acc0 = 0.f, acc1 = 0.f;
    #pragma unroll
    for (int chunk=0; chunk<8; ++chunk){
      u32 v = ub[chunk*256 + t];
      float wv = wlds[c][chunk*32 + nl];
      acc0 = fmaf(wv, blo(v), acc0);
      acc1 = fmaf(wv, bhi(v), acc1);
    }
    a0[c] = acc0; a1[c] = acc1;
  }
  #pragma unroll
  for (int c=0;c<10;++c){
    pacc[c][2*dp  ][nl] = a0[c];
    pacc[c][2*dp+1][nl] = a1[c];
  }
  __syncthreads();
  if (t < 160){
    const int c = t >> 4, d = t & 15;
    float acc = 0.f;
    #pragma unroll
    for (int j=0;j<32;++j) acc += pacc[c][d][j];
    spout[((size_t)b*36 + ch)*160 + t] = acc;
  }
}

// ---------------- head: squash(final) -> v (d_out) -> mask -> fc1 -> fc2 slice -> h2T
__global__ __launch_bounds__(256) void k_head(const float* __restrict__ y,
    const float* __restrict__ spin, const float* __restrict__ w1,
    const float* __restrict__ b1, const float* __restrict__ w2,
    const float* __restrict__ b2, float* __restrict__ dout_v,
    float* __restrict__ h2T){
  const int b = blockIdx.x;
  const int q = blockIdx.y;
  const int t = threadIdx.x;
  __shared__ float vl[160];
  __shared__ float sq[160];
  __shared__ float h1s[512];
  float sv = 0.f;
  if (t < 160){
    #pragma unroll 4
    for (int c2=0;c2<36;++c2) sv += spin[((size_t)b*36 + c2)*160 + t];
    sq[t] = sv*sv;
  }
  __syncthreads();
  if (t < 160){
    int cc = t >> 4;
    float ss = 0.f;
    #pragma unroll
    for (int j=0;j<16;++j) ss += sq[cc*16 + j];
    float nrm = sqrtf(ss);
    float vv = (ss/(1.f+ss)) * sv / (nrm + EPSQ);
    if (q == 0) dout_v[(size_t)b*160 + t] = vv;
    vl[t] = vv * y[b*10 + cc];
  }
  __syncthreads();
  #pragma unroll
  for (int j=0;j<2;++j){
    const int oc = j*256 + t;
    float acc = b1[oc];
    for (int k=0;k<160;++k) acc = fmaf(vl[k], w1[(size_t)k*512 + oc], acc);
    h1s[oc] = fmaxf(acc, 0.f);
  }
  __syncthreads();
  const int oc2 = q*256 + t;
  float acc = b2[oc2];
  for (int k=0;k<512;++k) acc = fmaf(h1s[k], w2[(size_t)k*1024 + oc2], acc);
  h2T[(size_t)oc2*32 + b] = fmaxf(acc, 0.f);
}

// ---------------- fc3 (1024->43200) K-split partials; h2T chunk staged in LDS (float4)
__global__ __launch_bounds__(256) void k_fc3p(const float* __restrict__ h2T,
    const float* __restrict__ w3, float* __restrict__ fp){
  __shared__ float4 hs4[128][8];
  const int t  = threadIdx.x;
  const int oc = blockIdx.x*256 + t;
  const int ks = blockIdx.y;   // 0..7, 128 k each
  const float4* src = reinterpret_cast<const float4*>(h2T + (size_t)ks*128*32);
  #pragma unroll
  for (int r=0;r<4;++r)
    (&hs4[0][0])[t + r*256] = src[t + r*256];
  __syncthreads();
  const bool ok = oc < 43200;
  float a[32];
  #pragma unroll
  for (int b=0;b<32;++b) a[b] = 0.f;
  const size_t wbase = (size_t)ks*128*43200 + (size_t)(ok ? oc : 0);
  #pragma unroll 4
  for (int k=0;k<128;++k){
    float wv = w3[wbase + (size_t)k*43200];
    #pragma unroll
    for (int q=0;q<8;++q){
      float4 hv = hs4[k][q];
      a[q*4+0] = fmaf(hv.x, wv, a[q*4+0]);
      a[q*4+1] = fmaf(hv.y, wv, a[q*4+1]);
      a[q*4+2] = fmaf(hv.z, wv, a[q*4+2]);
      a[q*4+3] = fmaf(hv.w, wv, a[q*4+3]);
    }
  }
  if (ok){
    #pragma unroll
    for (int b=0;b<32;++b) fp[(size_t)(ks*32 + b)*43200 + oc] = a[b];
  }
}

// ---------------- fc3 finalize + sigmoid -> d_out rec (float4)
__global__ __launch_bounds__(256) void k_fc3f(const float* __restrict__ fp,
    const float* __restrict__ b3, float* __restrict__ outr){
  const int i4 = blockIdx.x*256 + threadIdx.x;   // < 345600
  if (i4 >= 345600) return;
  const int b = i4 / 10800, oc4 = i4 - b*10800;
  const float4* b34 = reinterpret_cast<const float4*>(b3);
  float4 s = b34[oc4];
  const float4* fp4 = reinterpret_cast<const float4*>(fp);
  #pragma unroll
  for (int ks=0;ks<FC3SPL;++ks){
    float4 p = fp4[(size_t)(ks*32 + b)*10800 + oc4];
    s.x += p.x; s.y += p.y; s.z += p.z; s.w += p.w;
  }
  float4 o;
  o.x = 1.f/(1.f + __expf(-s.x));
  o.y = 1.f/(1.f + __expf(-s.y));
  o.z = 1.f/(1.f + __expf(-s.z));
  o.w = 1.f/(1.f + __expf(-s.w));
  reinterpret_cast<float4*>(outr)[i4] = o;
}

extern "C" void kernel_launch(void* const* d_in, const int* in_sizes, int n_in,
                              void* d_out, int out_size, void* d_ws, size_t ws_size,
                              hipStream_t stream){
  (void)in_sizes; (void)n_in; (void)out_size; (void)ws_size;
  const float* x     = (const float*)d_in[0];
  const float* y     = (const float*)d_in[1];
  const float* c1w   = (const float*)d_in[2];
  const float* c1b   = (const float*)d_in[3];
  const float* c2w   = (const float*)d_in[4];
  const float* c2b   = (const float*)d_in[5];
  const float* wpose = (const float*)d_in[6];
  const float* w1    = (const float*)d_in[7];
  const float* b1    = (const float*)d_in[8];
  const float* w2    = (const float*)d_in[9];
  const float* b2    = (const float*)d_in[10];
  const float* w3    = (const float*)d_in[11];
  const float* b3    = (const float*)d_in[12];
  float* out = (float*)d_out;

  char* ws = (char*)d_ws;
  u16*   a1bp  = (u16*)(ws + 0);            // 51.4 MB [dead after conv2]
  u16*   A1col = (u16*)(ws + 52000000);     // 51.4 MB [dead after gemm1]
  float* partp = (float*)(ws + 52000000);   // 84.9 MB [conv2 writes after A1col dead; dead after comb]
  u16*   uhatp = (u16*)(ws + 0);            // 94.4 MB [k_uhat runs after comb -> a1b & part dead]
  u16*   w1tp  = (u16*)(ws + 138000000);    // 131 KB
  u16*   w2tp  = (u16*)(ws + 138500000);    // 5.3 MB
  float* up    = (float*)(ws + 144000000);  // 9.4 MB
  float* logip = (float*)(ws + 154000000);  // 11.8 MB
  float* spA   = (float*)(ws + 166000000);  // 737 KB
  float* spB   = (float*)(ws + 166800000);  // 737 KB
  float* h2Tp  = (float*)(ws + 167600000);  // 131 KB
  float* fc3pp = (float*)(ws + 0);          // 44.2 MB [after uhat dead]

  k_im2col<<<dim3(12544),  256, 0, stream>>>(x, A1col);
  k_wt1   <<<dim3(8,8),    256, 0, stream>>>(c1w, w1tp);
  k_wt    <<<dim3(648,4),  256, 0, stream>>>(c2w, w2tp);
  k_gemm1 <<<dim3(784,2),  256, 0, stream>>>(A1col, w1tp, c1b, a1bp);
  k_conv2 <<<dim3(144,KSPLIT), 256, 0, stream>>>(a1bp, w2tp, partp);
  k_comb  <<<dim3(2304),   256, 0, stream>>>(partp, c2b, up);
  k_uhat  <<<dim3(9216),   256, 0, stream>>>(up, wpose, uhatp);

  k_route<1><<<dim3(36,32), 256, 0, stream>>>(uhatp, spB, logip, spA);
  k_route<2><<<dim3(36,32), 256, 0, stream>>>(uhatp, spA, logip, spB);
  k_route<3><<<dim3(36,32), 256, 0, stream>>>(uhatp, spB, logip, spA);

  k_head <<<dim3(32,4), 256, 0, stream>>>(y, spA, w1, b1, w2, b2, out, h2Tp);
  k_fc3p <<<dim3(169,FC3SPL), 256, 0, stream>>>(h2Tp, w3, fc3pp);
  k_fc3f <<<dim3(1350), 256, 0, stream>>>(fc3pp, b3, out + 5120);
}

// Round 13
// 520.448 us; speedup vs baseline: 1.0188x; 1.0188x over previous
//
#include <hip/hip_runtime.h>
#include <hip/hip_bf16.h>

typedef unsigned short u16;
typedef unsigned int   u32;
typedef __attribute__((ext_vector_type(8))) __bf16 bf16x8;
typedef __attribute__((ext_vector_type(4))) float  f32x4;

#define EPSQ 1e-7f
#define KSPLIT 9
#define KPB 2304
#define KSTEPS 36
#define FC3SPL 8

#define GLDS16(gp, lp) __builtin_amdgcn_global_load_lds( \
    (const __attribute__((address_space(1))) void*)(gp), \
    (__attribute__((address_space(3))) void*)(lp), 16, 0, 0)
#define WAITV8() asm volatile("s_waitcnt vmcnt(8)" ::: "memory")
#define WAITV4() asm volatile("s_waitcnt vmcnt(4)" ::: "memory")
#define WAITV0() asm volatile("s_waitcnt vmcnt(0)" ::: "memory")

__device__ __forceinline__ u16 f2bf(float f){
  u32 u = __float_as_uint(f);
  u32 r = (u + 0x7fffu + ((u >> 16) & 1u)) >> 16;
  return (u16)r;
}
__device__ __forceinline__ float bf2f(u16 h){ return __uint_as_float(((u32)h) << 16); }
__device__ __forceinline__ float blo(u32 w){ return __uint_as_float(w << 16); }
__device__ __forceinline__ float bhi(u32 w){ return __uint_as_float(w & 0xffff0000u); }

// ---------------- fused prep: im2col (blocks 0..12543) | wt1 (12544..12607) | wt (12608..15199)
__global__ __launch_bounds__(256) void k_prep(const float* __restrict__ x, u16* __restrict__ A1,
    const float* __restrict__ w1, u16* __restrict__ wt1,
    const float* __restrict__ w2, u16* __restrict__ wt2){
  __shared__ float tile[32][33];
  const int bid = blockIdx.x;
  const int t = threadIdx.x;
  if (bid < 12544){
    // im2col: A1[m][k] bf16, k=(ky*9+kx)*3+ic (<243), pad to 256
    const int id = bid*256 + t;
    const int m  = id >> 5;
    const int s  = id & 31;
    const int b  = m / 3136;
    const int r  = m - b*3136;
    const int oy = r / 56;
    const int ox = r - oy*56;
    const float* xb = x + ((size_t)b*120 + 2*oy)*120*3 + 2*ox*3;
    u16 vals[8];
    #pragma unroll
    for (int j=0;j<8;++j){
      int k = s*8 + j;
      if (k < 243){
        int ky = k / 27;
        int rem = k - ky*27;
        vals[j] = f2bf(xb[(size_t)ky*360 + rem]);
      } else vals[j] = 0;
    }
    *reinterpret_cast<uint4*>(A1 + (size_t)m*256 + s*8) = *reinterpret_cast<uint4*>(vals);
  } else if (bid < 12608){
    // transpose+pad conv1_w (243,256) f32 -> (256,256) bf16
    const int idx = bid - 12544;
    const int k0 = (idx >> 3)*32;
    const int c0 = (idx & 7)*32;
    const int c  = t & 31;
    const int r8 = t >> 5;
    #pragma unroll
    for (int rr=0; rr<4; ++rr){
      int r = r8*4+rr;
      tile[r][c] = (k0+r < 243) ? w1[(size_t)(k0+r)*256 + c0 + c] : 0.f;
    }
    __syncthreads();
    #pragma unroll
    for (int rr=0; rr<4; ++rr){
      int r = r8*4+rr;
      wt1[(size_t)(c0+r)*256 + k0 + c] = f2bf(tile[c][r]);
    }
  } else {
    // transpose conv2_w (20736,128) f32 -> (128,20736) bf16
    const int idx = bid - 12608;          // 2592 = 648*4
    const int k0 = (idx >> 2)*32;
    const int c0 = (idx & 3)*32;
    const int c  = t & 31;
    const int r8 = t >> 5;
    #pragma unroll
    for (int rr=0; rr<4; ++rr){
      int r = r8*4+rr;
      tile[r][c] = w2[(size_t)(k0+r)*128 + c0 + c];
    }
    __syncthreads();
    #pragma unroll
    for (int rr=0; rr<4; ++rr){
      int r = r8*4+rr;
      wt2[(size_t)(c0+r)*20736 + k0 + c] = f2bf(tile[c][r]);
    }
  }
}

// ---------------- conv1 GEMM: M=100352, N=256, K=256 ; BK=32, depth-3, dual-swizzled
__global__ __launch_bounds__(256) void k_gemm1(const u16* __restrict__ A1,
    const u16* __restrict__ w1t, const float* __restrict__ bias, u16* __restrict__ a1b){
  __shared__ __align__(16) u16 As[3][4096];
  __shared__ __align__(16) u16 Bs[3][4096];
  const int t  = threadIdx.x;
  const int bx = blockIdx.x;   // 784
  const int by = blockIdx.y;   // 2
  const int row0  = t>>2;
  const int sslot = (t&3) ^ ((t>>3)&3);      // pre-swizzled source k-slot
  const int wid = t>>6, lane = t&63;
  const int wr = wid>>1, wc = wid&1, lr = lane&15, lq = lane>>4;
  const int sl = lq ^ ((lr>>1)&3);           // swizzled read k-slot
  const size_t srcA0 = (size_t)(bx*128 + row0)*256 + sslot*8;
  const size_t srcA1 = srcA0 + (size_t)64*256;
  const size_t srcB0 = (size_t)(by*128 + row0)*256 + sslot*8;
  const size_t srcB1 = srcB0 + (size_t)64*256;
  f32x4 acc[4][4];
  #pragma unroll
  for (int i=0;i<4;++i)
    #pragma unroll
    for (int j=0;j<4;++j) acc[i][j] = (f32x4){0.f,0.f,0.f,0.f};
  int aoff[4], boff[4];
  #pragma unroll
  for (int i=0;i<4;++i){
    aoff[i] = (wr*64 + i*16 + lr)*32 + sl*8;
    boff[i] = (wc*64 + i*16 + lr)*32 + sl*8;
  }

  auto stage = [&](int step, int buf){
    const int k0 = step*32;
    GLDS16(A1 + srcA0 + k0, &As[buf][wid*512]);
    GLDS16(A1 + srcA1 + k0, &As[buf][wid*512 + 2048]);
    GLDS16(w1t + srcB0 + k0, &Bs[buf][wid*512]);
    GLDS16(w1t + srcB1 + k0, &Bs[buf][wid*512 + 2048]);
  };
  auto compute = [&](int buf){
    bf16x8 af[4], bfv[4];
    #pragma unroll
    for (int mi=0;mi<4;++mi)
      af[mi] = *reinterpret_cast<const bf16x8*>(&As[buf][aoff[mi]]);
    #pragma unroll
    for (int ni=0;ni<4;++ni)
      bfv[ni] = *reinterpret_cast<const bf16x8*>(&Bs[buf][boff[ni]]);
    #pragma unroll
    for (int mi=0;mi<4;++mi)
      #pragma unroll
      for (int ni=0;ni<4;++ni)
        acc[mi][ni] = __builtin_amdgcn_mfma_f32_16x16x32_bf16(af[mi], bfv[ni], acc[mi][ni], 0, 0, 0);
  };

  stage(0, 0);
  stage(1, 1);
  for (int step=0; step<8; ++step){
    if (step+2 < 8){
      stage(step+2, (step+2)%3);
      WAITV8();
    } else if (step+1 < 8){
      WAITV4();
    } else {
      WAITV0();
    }
    __builtin_amdgcn_s_barrier();
    __builtin_amdgcn_sched_barrier(0);
    compute(step%3);
    __builtin_amdgcn_s_barrier();
    __builtin_amdgcn_sched_barrier(0);
  }

  #pragma unroll
  for (int ni=0;ni<4;++ni){
    int colg = by*128 + wc*64 + ni*16 + lr;
    float bv = bias[colg];
    #pragma unroll
    for (int mi=0;mi<4;++mi){
      #pragma unroll
      for (int r=0;r<4;++r){
        int rowg = bx*128 + wr*64 + mi*16 + lq*4 + r;
        float v = fmaxf(acc[mi][ni][r] + bv, 0.f);
        a1b[(size_t)rowg*256 + colg] = f2bf(v);
      }
    }
  }
}

// ---------------- conv2 implicit GEMM: M=18432, N=128, K=20736 ; BK=64, depth-2, dual-swizzled
__global__ __launch_bounds__(256) void k_conv2(const u16* __restrict__ a1b,
    const u16* __restrict__ w2t, float* __restrict__ part){
  __shared__ __align__(16) u16 As[2][8192];   // [128 rows][64 k]
  __shared__ __align__(16) u16 Bs[2][8192];
  const int t  = threadIdx.x;
  const int bx = blockIdx.x;   // 0..143
  const int ks = blockIdx.y;   // 0..KSPLIT-1 (= ky)
  const int r8 = t>>3;
  const int sslot = (t&7) ^ (r8&7);
  int gA[4]; int gB[4];
  #pragma unroll
  for (int i=0;i<4;++i){
    int m  = bx*128 + i*32 + r8;
    int bb = m/576; int r = m - bb*576; int oy = r/24; int ox = r - oy*24;
    gA[i] = ((bb*56 + 2*oy)*56 + 2*ox)*256 + sslot*8;
    int col = i*32 + r8;
    gB[i] = col*20736 + sslot*8;
  }
  const int wid = t>>6, lane = t&63;
  const int wr = wid>>1, wc = wid&1, lr = lane&15, lq = lane>>4;
  f32x4 acc[4][4];
  #pragma unroll
  for (int i=0;i<4;++i)
    #pragma unroll
    for (int j=0;j<4;++j) acc[i][j] = (f32x4){0.f,0.f,0.f,0.f};
  const int kbase = ks*KPB;

  auto stage = [&](int step, int buf){
    const int kx  = step >> 2;
    const int ic0 = (step & 3) * 64;
    const int soff = (ks*56 + kx)*256 + ic0;
    const int k0b  = kbase + step*64;
    #pragma unroll
    for (int i=0;i<4;++i)
      GLDS16(a1b + gA[i] + soff, &As[buf][i*2048 + wid*512]);
    #pragma unroll
    for (int i=0;i<4;++i)
      GLDS16(w2t + gB[i] + k0b, &Bs[buf][i*2048 + wid*512]);
  };
  auto compute = [&](int buf){
    #pragma unroll
    for (int ksub=0;ksub<2;++ksub){
      const int ps = (((ksub<<2)|lq) ^ (lr&7))*8;
      bf16x8 af[4], bfv[4];
      #pragma unroll
      for (int mi=0;mi<4;++mi)
        af[mi] = *reinterpret_cast<const bf16x8*>(&As[buf][(wr*64 + mi*16 + lr)*64 + ps]);
      #pragma unroll
      for (int ni=0;ni<4;++ni)
        bfv[ni] = *reinterpret_cast<const bf16x8*>(&Bs[buf][(wc*64 + ni*16 + lr)*64 + ps]);
      #pragma unroll
      for (int mi=0;mi<4;++mi)
        #pragma unroll
        for (int ni=0;ni<4;++ni)
          acc[mi][ni] = __builtin_amdgcn_mfma_f32_16x16x32_bf16(af[mi], bfv[ni], acc[mi][ni], 0, 0, 0);
    }
  };

  stage(0, 0);
  int cur = 0;
  for (int step=0; step<KSTEPS; ++step){
    if (step+1 < KSTEPS){
      stage(step+1, cur^1);
      WAITV8();
    } else {
      WAITV0();
    }
    __builtin_amdgcn_s_barrier();
    __builtin_amdgcn_sched_barrier(0);
    compute(cur);
    __builtin_amdgcn_s_barrier();
    __builtin_amdgcn_sched_barrier(0);
    cur ^= 1;
  }

  const size_t base = ((size_t)ks*18432 + (size_t)bx*128)*128;
  #pragma unroll
  for (int mi=0;mi<4;++mi){
    #pragma unroll
    for (int ni=0;ni<4;++ni){
      int col = wc*64 + ni*16 + lr;
      #pragma unroll
      for (int r=0;r<4;++r){
        int row = wr*64 + mi*16 + lq*4 + r;
        part[base + (size_t)row*128 + col] = acc[mi][ni][r];
      }
    }
  }
}

// ---------------- combine K-split partials + bias -> u (fp32), float4
__global__ __launch_bounds__(256) void k_comb(const float* __restrict__ part,
    const float* __restrict__ bias, float* __restrict__ u){
  const int i4 = blockIdx.x*256 + threadIdx.x;   // < 589824
  const float4* b4 = reinterpret_cast<const float4*>(bias);
  float4 s = b4[i4 & 31];
  const float4* p4 = reinterpret_cast<const float4*>(part);
  #pragma unroll
  for (int ks=0; ks<KSPLIT; ++ks){
    float4 p = p4[(size_t)ks*589824 + i4];
    s.x += p.x; s.y += p.y; s.z += p.z; s.w += p.w;
  }
  reinterpret_cast<float4*>(u)[i4] = s;
}

// ---------------- u_hat[b,c,n,d] (bf16) = sum_p W[n,c,d,p] * u[b,n,p]
__global__ __launch_bounds__(256) void k_uhat(const float* __restrict__ u,
    const float* __restrict__ wpose, u16* __restrict__ uhat){
  __shared__ float Wn[1280];
  __shared__ float us[256];
  const int n = blockIdx.x;
  const int t = threadIdx.x;
  #pragma unroll
  for (int j=0;j<5;++j) Wn[t + j*256] = wpose[(size_t)n*1280 + t + j*256];
  us[t] = u[((size_t)(t>>3)*9216 + n)*8 + (t&7)];
  __syncthreads();
  const int b = t>>3, d0 = (t&7)*2;
  float uv[8];
  #pragma unroll
  for (int p=0;p<8;++p) uv[p] = us[b*8+p];
  for (int c=0;c<10;++c){
    const float* w0 = &Wn[(c*16 + d0)*8];
    float v0=0.f, v1=0.f;
    #pragma unroll
    for (int p=0;p<8;++p){ v0 = fmaf(w0[p], uv[p], v0); v1 = fmaf(w0[8+p], uv[p], v1); }
    u32 pk = (u32)f2bf(v0) | ((u32)f2bf(v1) << 16);
    *reinterpret_cast<u32*>(uhat + ((((size_t)b*10 + c)*9216 + n)*16 + d0)) = pk;
  }
}

// ---------------- fused routing iteration (in-block squash of previous spart)
// spart layout: [b][ch][160]
template<int ITER>
__global__ __launch_bounds__(256) void k_route(const u16* __restrict__ uhat,
    const float* __restrict__ spin, float* __restrict__ logi,
    float* __restrict__ spout){
  const int ch = blockIdx.x;   // 36 chunks of 256 n
  const int b  = blockIdx.y;   // 32
  const int t  = threadIdx.x;
  const int n  = ch*256 + t;
  __shared__ float vl[160];
  __shared__ float sq[160];
  __shared__ float wlds[10][257];
  __shared__ float pacc[10][16][33];
  if (ITER >= 2){
    float sv = 0.f;
    if (t < 160){
      #pragma unroll 4
      for (int c2=0;c2<36;++c2) sv += spin[((size_t)b*36 + c2)*160 + t];
      sq[t] = sv*sv;
    }
    __syncthreads();
    if (t < 160){
      int cc = t >> 4;
      float ss = 0.f;
      #pragma unroll
      for (int j=0;j<16;++j) ss += sq[cc*16 + j];
      float nrm = sqrtf(ss);
      vl[t] = (ss/(1.f+ss)) * sv / (nrm + EPSQ);
    }
    __syncthreads();
  }
  float w[10];
  if (ITER == 1){
    #pragma unroll
    for (int c=0;c<10;++c) w[c] = 0.1f;
  } else {
    float l[10];
    #pragma unroll
    for (int c=0;c<10;++c){
      const u16* up = uhat + ((((size_t)b*10 + c)*9216 + n) << 4);
      const uint4 q0 = *reinterpret_cast<const uint4*>(up);
      const uint4 q1 = *reinterpret_cast<const uint4*>(up + 8);
      const float* v = &vl[c*16];
      float dot = blo(q0.x)*v[0] + bhi(q0.x)*v[1]
                + blo(q0.y)*v[2] + bhi(q0.y)*v[3]
                + blo(q0.z)*v[4] + bhi(q0.z)*v[5]
                + blo(q0.w)*v[6] + bhi(q0.w)*v[7]
                + blo(q1.x)*v[8] + bhi(q1.x)*v[9]
                + blo(q1.y)*v[10]+ bhi(q1.y)*v[11]
                + blo(q1.z)*v[12]+ bhi(q1.z)*v[13]
                + blo(q1.w)*v[14]+ bhi(q1.w)*v[15];
      size_t li = ((size_t)b*10 + c)*9216 + n;
      float lc = dot;
      if (ITER == 3) lc += logi[li];
      if (ITER == 2) logi[li] = lc;
      l[c] = lc;
    }
    float mx = l[0];
    #pragma unroll
    for (int c=1;c<10;++c) mx = fmaxf(mx, l[c]);
    float s = 0.f;
    #pragma unroll
    for (int c=0;c<10;++c){ w[c] = __expf(l[c]-mx); s += w[c]; }
    float inv = 1.f/s;
    #pragma unroll
    for (int c=0;c<10;++c) w[c] *= inv;
  }
  #pragma unroll
  for (int c=0;c<10;++c) wlds[c][t] = w[c];
  __syncthreads();

  const int nl = t>>3, dp = t&7;
  float a0[10], a1[10];
  #pragma unroll
  for (int c=0;c<10;++c){ a0[c]=0.f; a1[c]=0.f; }
  #pragma unroll
  for (int c=0;c<10;++c){
    const u32* ub = reinterpret_cast<const u32*>(
        uhat + ((((size_t)b*10 + c)*9216 + (size_t)ch*256) << 4));
    float acc0 = 0.f, acc1 = 0.f;
    #pragma unroll
    for (int chunk=0; chunk<8; ++chunk){
      u32 v = ub[chunk*256 + t];
      float wv = wlds[c][chunk*32 + nl];
      acc0 = fmaf(wv, blo(v), acc0);
      acc1 = fmaf(wv, bhi(v), acc1);
    }
    a0[c] = acc0; a1[c] = acc1;
  }
  #pragma unroll
  for (int c=0;c<10;++c){
    pacc[c][2*dp  ][nl] = a0[c];
    pacc[c][2*dp+1][nl] = a1[c];
  }
  __syncthreads();
  if (t < 160){
    const int c = t >> 4, d = t & 15;
    float acc = 0.f;
    #pragma unroll
    for (int j=0;j<32;++j) acc += pacc[c][d][j];
    spout[((size_t)b*36 + ch)*160 + t] = acc;
  }
}

// ---------------- head: squash(final) -> v (d_out) -> mask -> fc1 -> fc2 slice -> h2T
__global__ __launch_bounds__(256) void k_head(const float* __restrict__ y,
    const float* __restrict__ spin, const float* __restrict__ w1,
    const float* __restrict__ b1, const float* __restrict__ w2,
    const float* __restrict__ b2, float* __restrict__ dout_v,
    float* __restrict__ h2T){
  const int b = blockIdx.x;
  const int q = blockIdx.y;
  const int t = threadIdx.x;
  __shared__ float vl[160];
  __shared__ float sq[160];
  __shared__ float h1s[512];
  float sv = 0.f;
  if (t < 160){
    #pragma unroll 4
    for (int c2=0;c2<36;++c2) sv += spin[((size_t)b*36 + c2)*160 + t];
    sq[t] = sv*sv;
  }
  __syncthreads();
  if (t < 160){
    int cc = t >> 4;
    float ss = 0.f;
    #pragma unroll
    for (int j=0;j<16;++j) ss += sq[cc*16 + j];
    float nrm = sqrtf(ss);
    float vv = (ss/(1.f+ss)) * sv / (nrm + EPSQ);
    if (q == 0) dout_v[(size_t)b*160 + t] = vv;
    vl[t] = vv * y[b*10 + cc];
  }
  __syncthreads();
  #pragma unroll
  for (int j=0;j<2;++j){
    const int oc = j*256 + t;
    float acc = b1[oc];
    for (int k=0;k<160;++k) acc = fmaf(vl[k], w1[(size_t)k*512 + oc], acc);
    h1s[oc] = fmaxf(acc, 0.f);
  }
  __syncthreads();
  const int oc2 = q*256 + t;
  float acc = b2[oc2];
  for (int k=0;k<512;++k) acc = fmaf(h1s[k], w2[(size_t)k*1024 + oc2], acc);
  h2T[(size_t)oc2*32 + b] = fmaxf(acc, 0.f);
}

// ---------------- fc3 (1024->43200) K-split partials; h2T chunk staged in LDS (float4)
__global__ __launch_bounds__(256) void k_fc3p(const float* __restrict__ h2T,
    const float* __restrict__ w3, float* __restrict__ fp){
  __shared__ float4 hs4[128][8];
  const int t  = threadIdx.x;
  const int oc = blockIdx.x*256 + t;
  const int ks = blockIdx.y;   // 0..7, 128 k each
  const float4* src = reinterpret_cast<const float4*>(h2T + (size_t)ks*128*32);
  #pragma unroll
  for (int r=0;r<4;++r)
    (&hs4[0][0])[t + r*256] = src[t + r*256];
  __syncthreads();
  const bool ok = oc < 43200;
  float a[32];
  #pragma unroll
  for (int b=0;b<32;++b) a[b] = 0.f;
  const size_t wbase = (size_t)ks*128*43200 + (size_t)(ok ? oc : 0);
  #pragma unroll 4
  for (int k=0;k<128;++k){
    float wv = w3[wbase + (size_t)k*43200];
    #pragma unroll
    for (int q=0;q<8;++q){
      float4 hv = hs4[k][q];
      a[q*4+0] = fmaf(hv.x, wv, a[q*4+0]);
      a[q*4+1] = fmaf(hv.y, wv, a[q*4+1]);
      a[q*4+2] = fmaf(hv.z, wv, a[q*4+2]);
      a[q*4+3] = fmaf(hv.w, wv, a[q*4+3]);
    }
  }
  if (ok){
    #pragma unroll
    for (int b=0;b<32;++b) fp[(size_t)(ks*32 + b)*43200 + oc] = a[b];
  }
}

// ---------------- fc3 finalize + sigmoid -> d_out rec (float4)
__global__ __launch_bounds__(256) void k_fc3f(const float* __restrict__ fp,
    const float* __restrict__ b3, float* __restrict__ outr){
  const int i4 = blockIdx.x*256 + threadIdx.x;   // < 345600
  if (i4 >= 345600) return;
  const int b = i4 / 10800, oc4 = i4 - b*10800;
  const float4* b34 = reinterpret_cast<const float4*>(b3);
  float4 s = b34[oc4];
  const float4* fp4 = reinterpret_cast<const float4*>(fp);
  #pragma unroll
  for (int ks=0;ks<FC3SPL;++ks){
    float4 p = fp4[(size_t)(ks*32 + b)*10800 + oc4];
    s.x += p.x; s.y += p.y; s.z += p.z; s.w += p.w;
  }
  float4 o;
  o.x = 1.f/(1.f + __expf(-s.x));
  o.y = 1.f/(1.f + __expf(-s.y));
  o.z = 1.f/(1.f + __expf(-s.z));
  o.w = 1.f/(1.f + __expf(-s.w));
  reinterpret_cast<float4*>(outr)[i4] = o;
}

extern "C" void kernel_launch(void* const* d_in, const int* in_sizes, int n_in,
                              void* d_out, int out_size, void* d_ws, size_t ws_size,
                              hipStream_t stream){
  (void)in_sizes; (void)n_in; (void)out_size; (void)ws_size;
  const float* x     = (const float*)d_in[0];
  const float* y     = (const float*)d_in[1];
  const float* c1w   = (const float*)d_in[2];
  const float* c1b   = (const float*)d_in[3];
  const float* c2w   = (const float*)d_in[4];
  const float* c2b   = (const float*)d_in[5];
  const float* wpose = (const float*)d_in[6];
  const float* w1    = (const float*)d_in[7];
  const float* b1    = (const float*)d_in[8];
  const float* w2    = (const float*)d_in[9];
  const float* b2    = (const float*)d_in[10];
  const float* w3    = (const float*)d_in[11];
  const float* b3    = (const float*)d_in[12];
  float* out = (float*)d_out;

  char* ws = (char*)d_ws;
  u16*   a1bp  = (u16*)(ws + 0);            // 51.4 MB [dead after conv2]
  u16*   A1col = (u16*)(ws + 52000000);     // 51.4 MB [dead after gemm1]
  float* partp = (float*)(ws + 52000000);   // 84.9 MB [conv2 writes after A1col dead; dead after comb]
  u16*   uhatp = (u16*)(ws + 0);            // 94.4 MB [k_uhat runs after comb -> a1b & part dead]
  u16*   w1tp  = (u16*)(ws + 138000000);    // 131 KB
  u16*   w2tp  = (u16*)(ws + 138500000);    // 5.3 MB
  float* up    = (float*)(ws + 144000000);  // 9.4 MB
  float* logip = (float*)(ws + 154000000);  // 11.8 MB
  float* spA   = (float*)(ws + 166000000);  // 737 KB
  float* spB   = (float*)(ws + 166800000);  // 737 KB
  float* h2Tp  = (float*)(ws + 167600000);  // 131 KB
  float* fc3pp = (float*)(ws + 0);          // 44.2 MB [after uhat dead]

  k_prep  <<<dim3(15200), 256, 0, stream>>>(x, A1col, c1w, w1tp, c2w, w2tp);
  k_gemm1 <<<dim3(784,2), 256, 0, stream>>>(A1col, w1tp, c1b, a1bp);
  k_conv2 <<<dim3(144,KSPLIT), 256, 0, stream>>>(a1bp, w2tp, partp);
  k_comb  <<<dim3(2304),  256, 0, stream>>>(partp, c2b, up);
  k_uhat  <<<dim3(9216),  256, 0, stream>>>(up, wpose, uhatp);

  k_route<1><<<dim3(36,32), 256, 0, stream>>>(uhatp, spB, logip, spA);
  k_route<2><<<dim3(36,32), 256, 0, stream>>>(uhatp, spA, logip, spB);
  k_route<3><<<dim3(36,32), 256, 0, stream>>>(uhatp, spB, logip, spA);

  k_head <<<dim3(32,4), 256, 0, stream>>>(y, spA, w1, b1, w2, b2, out, h2Tp);
  k_fc3p <<<dim3(169,FC3SPL), 256, 0, stream>>>(h2Tp, w3, fc3pp);
  k_fc3f <<<dim3(1350), 256, 0, stream>>>(fc3pp, b3, out + 5120);
}